// Round 1
// baseline (4787.955 us; speedup 1.0000x reference)
//
#include <hip/hip_runtime.h>
#include <cmath>

typedef float  f32x4  __attribute__((ext_vector_type(4)));
typedef __bf16 bf16x8 __attribute__((ext_vector_type(8)));

static constexpr int HN  = 1024;     // hidden
static constexpr int VN  = 32000;    // vocab
static constexpr int BN  = 8;        // batch
static constexpr int SN  = 256;      // seq
static constexpr int H4N = 4096;     // 4*H

// ---------------------------------------------------------------------------
// xp0[t][b][r] = w_ih0[r][x[b][t]] + b_ih0[r] + b_hh0[r]
// grid: S*B blocks (bid = t*8+b), 256 threads
// ---------------------------------------------------------------------------
__global__ __launch_bounds__(256) void k_gather(const int* __restrict__ x,
    const float* __restrict__ w_ih0, const float* __restrict__ b_ih0,
    const float* __restrict__ b_hh0, float* __restrict__ xp) {
  int bid = blockIdx.x;
  int t = bid >> 3, b = bid & 7;
  int tok = x[b * SN + t];
  const float* col = w_ih0 + tok;           // column tok, stride VN
  float* dst = xp + (size_t)bid * H4N;
  for (int r = threadIdx.x; r < H4N; r += 256)
    dst[r] = col[(size_t)r * VN] + b_ih0[r] + b_hh0[r];
}

// ---------------------------------------------------------------------------
// One LSTM time step. grid: 256 blocks (4 hidden units each), 256 threads.
// thread = (ks, u, b): partial dot over k in [ks*128, ks*128+128) for the
// 4 gate rows {g*H + unit} of unit = blockIdx.x*4+u, batch b.
// ---------------------------------------------------------------------------
__global__ __launch_bounds__(256) void k_step(const float* __restrict__ xp_t,
    const float* __restrict__ w_hh, const float* __restrict__ h_in,
    float* __restrict__ h_out, const float* __restrict__ c_in,
    float* __restrict__ c_out, float* __restrict__ hs_out,
    float* __restrict__ hn_out, float* __restrict__ cn_out, int is_last) {
  __shared__ float h_lds[BN][HN + 4];          // +4 pad: bank-spread over b
  __shared__ float red[8][4][4][8];            // [ks][u][g][b]
  __shared__ float gates[4][4][8];             // [u][g][b]
  int tid = threadIdx.x;

  // stage h_in [8][1024] into LDS (coalesced float4)
  #pragma unroll
  for (int j = 0; j < 8; ++j) {
    int f4 = j * 256 + tid;                    // float4 index; row = j
    f32x4 v = *(const f32x4*)&h_in[f4 * 4];
    *(f32x4*)&h_lds[j][(f4 & 255) * 4] = v;
  }
  __syncthreads();

  int ks = tid >> 5, u = (tid >> 3) & 3, b = tid & 7;
  int unit = blockIdx.x * 4 + u;
  const float* w0 = w_hh + (size_t)unit * HN;            // gate i row
  const float* w1 = w0 + (size_t)HN * HN;                // gate f
  const float* w2 = w1 + (size_t)HN * HN;                // gate g
  const float* w3 = w2 + (size_t)HN * HN;                // gate o
  int k0 = ks * 128;
  float a0 = 0.f, a1 = 0.f, a2 = 0.f, a3 = 0.f;
  #pragma unroll 8
  for (int i = 0; i < 32; ++i) {
    int k = k0 + i * 4;
    f32x4 hv = *(const f32x4*)&h_lds[b][k];
    f32x4 wv;
    wv = *(const f32x4*)&w0[k]; a0 += hv[0]*wv[0]+hv[1]*wv[1]+hv[2]*wv[2]+hv[3]*wv[3];
    wv = *(const f32x4*)&w1[k]; a1 += hv[0]*wv[0]+hv[1]*wv[1]+hv[2]*wv[2]+hv[3]*wv[3];
    wv = *(const f32x4*)&w2[k]; a2 += hv[0]*wv[0]+hv[1]*wv[1]+hv[2]*wv[2]+hv[3]*wv[3];
    wv = *(const f32x4*)&w3[k]; a3 += hv[0]*wv[0]+hv[1]*wv[1]+hv[2]*wv[2]+hv[3]*wv[3];
  }
  red[ks][u][0][b] = a0;
  red[ks][u][1][b] = a1;
  red[ks][u][2][b] = a2;
  red[ks][u][3][b] = a3;
  __syncthreads();

  if (tid < 128) {                              // one thread per (gate-row, b)
    int rid = tid >> 3, bb = tid & 7;
    int uu = rid >> 2, g = rid & 3;
    float s = 0.f;
    #pragma unroll
    for (int q = 0; q < 8; ++q) s += red[q][uu][g][bb];
    gates[uu][g][bb] = s + xp_t[bb * H4N + g * HN + blockIdx.x * 4 + uu];
  }
  __syncthreads();

  if (tid < 32) {                               // one thread per (unit, b)
    int uu = tid >> 3, bb = tid & 7;
    int un = blockIdx.x * 4 + uu;
    float gi = gates[uu][0][bb], gf = gates[uu][1][bb];
    float gg = gates[uu][2][bb], go = gates[uu][3][bb];
    float c_old = c_in[bb * HN + un];
    float si = 1.f / (1.f + expf(-gi));
    float sf = 1.f / (1.f + expf(-gf));
    float so = 1.f / (1.f + expf(-go));
    float c = sf * c_old + si * tanhf(gg);
    float h = so * tanhf(c);
    c_out[bb * HN + un] = c;
    h_out[bb * HN + un] = h;
    hs_out[bb * HN + un] = h;
    if (is_last) { hn_out[bb * HN + un] = h; cn_out[bb * HN + un] = c; }
  }
}

// ---------------------------------------------------------------------------
// fp32 -> (bf16 hi, bf16 lo) split. n = 2048*1024, grid 2048 x 256, 4 elem/thr
// ---------------------------------------------------------------------------
__global__ __launch_bounds__(256) void k_split(const float* __restrict__ src,
    __bf16* __restrict__ hi, __bf16* __restrict__ lo) {
  int i = (blockIdx.x * 256 + threadIdx.x) * 4;
  f32x4 v = *(const f32x4*)&src[i];
  #pragma unroll
  for (int j = 0; j < 4; ++j) {
    __bf16 h = (__bf16)v[j];
    hi[i + j] = h;
    lo[i + j] = (__bf16)(v[j] - (float)h);
  }
}

// ---------------------------------------------------------------------------
// C[M=2048][N] = A[2048][1024] * Bsrc[N][1024]^T + bias1(+bias2), via
// 3-term bf16 split MFMA: AhiBhi + AhiBlo + AloBhi. 128x128 tile, BK=32,
// 4 waves (2x2 of 64x64), reg-staged B conversion fp32->bf16 hi/lo.
// permute=1: output row m=t*8+b is written to row b*256+t (logits layout).
// ---------------------------------------------------------------------------
__global__ __launch_bounds__(256) void k_gemm(const __bf16* __restrict__ Ahi,
    const __bf16* __restrict__ Alo, const float* __restrict__ Bsrc,
    const float* __restrict__ bias1, const float* __restrict__ bias2,
    float* __restrict__ C, int Mt, int N, int permute) {
  __shared__ __bf16 sAh[128][32], sAl[128][32], sBh[128][32], sBl[128][32];
  int bid = blockIdx.x;
  int tn = bid / Mt, tm = bid % Mt;           // m-fastest: B-strip L2 reuse
  int tid = threadIdx.x, lane = tid & 63, wid = tid >> 6;
  int wr = wid >> 1, wc = wid & 1;
  f32x4 acc[4][4] = {};
  const size_t K = 1024;

  for (int kk = 0; kk < 1024; kk += 32) {
    __syncthreads();
    #pragma unroll
    for (int it = 0; it < 2; ++it) {
      int c = it * 256 + tid;                  // 512 chunks of bf16x8
      int r = c >> 2, k8 = (c & 3) * 8;
      size_t ga = (size_t)(tm * 128 + r) * K + kk + k8;
      *(bf16x8*)&sAh[r][k8] = *(const bf16x8*)&Ahi[ga];
      *(bf16x8*)&sAl[r][k8] = *(const bf16x8*)&Alo[ga];
      size_t gb = (size_t)(tn * 128 + r) * K + kk + k8;
      f32x4 x0 = *(const f32x4*)&Bsrc[gb];
      f32x4 x1 = *(const f32x4*)&Bsrc[gb + 4];
      bf16x8 bh, bl;
      #pragma unroll
      for (int j = 0; j < 4; ++j) {
        __bf16 h0 = (__bf16)x0[j]; bh[j]     = h0; bl[j]     = (__bf16)(x0[j] - (float)h0);
        __bf16 h1 = (__bf16)x1[j]; bh[4 + j] = h1; bl[4 + j] = (__bf16)(x1[j] - (float)h1);
      }
      *(bf16x8*)&sBh[r][k8] = bh;
      *(bf16x8*)&sBl[r][k8] = bl;
    }
    __syncthreads();

    int kq = (lane >> 4) * 8;
    bf16x8 ah[4], al[4], bh[4], bl[4];
    #pragma unroll
    for (int i = 0; i < 4; ++i) {
      int ra = wr * 64 + i * 16 + (lane & 15);
      ah[i] = *(const bf16x8*)&sAh[ra][kq];
      al[i] = *(const bf16x8*)&sAl[ra][kq];
      int rb = wc * 64 + i * 16 + (lane & 15);
      bh[i] = *(const bf16x8*)&sBh[rb][kq];
      bl[i] = *(const bf16x8*)&sBl[rb][kq];
    }
    #pragma unroll
    for (int i = 0; i < 4; ++i)
      #pragma unroll
      for (int j = 0; j < 4; ++j) {
        acc[i][j] = __builtin_amdgcn_mfma_f32_16x16x32_bf16(ah[i], bh[j], acc[i][j], 0, 0, 0);
        acc[i][j] = __builtin_amdgcn_mfma_f32_16x16x32_bf16(ah[i], bl[j], acc[i][j], 0, 0, 0);
        acc[i][j] = __builtin_amdgcn_mfma_f32_16x16x32_bf16(al[i], bh[j], acc[i][j], 0, 0, 0);
      }
  }

  // epilogue: C/D layout col=lane&15, row=(lane>>4)*4+reg (m89-verified)
  #pragma unroll
  for (int j = 0; j < 4; ++j) {
    int gcol = tn * 128 + wc * 64 + j * 16 + (lane & 15);
    float bv = bias1[gcol] + (bias2 ? bias2[gcol] : 0.f);
    #pragma unroll
    for (int i = 0; i < 4; ++i) {
      #pragma unroll
      for (int r = 0; r < 4; ++r) {
        int row = tm * 128 + wr * 64 + i * 16 + ((lane >> 4) << 2) + r;
        int orow = permute ? ((row & 7) * 256 + (row >> 3)) : row;
        C[(size_t)orow * N + gcol] = acc[i][j][r] + bv;
      }
    }
  }
}

// ---------------------------------------------------------------------------
extern "C" void kernel_launch(void* const* d_in, const int* in_sizes, int n_in,
                              void* d_out, int out_size, void* d_ws, size_t ws_size,
                              hipStream_t stream) {
  (void)in_sizes; (void)n_in; (void)out_size; (void)ws_size;
  const int*   x     = (const int*)  d_in[0];
  const float* h0    = (const float*)d_in[1];
  const float* c0    = (const float*)d_in[2];
  const float* w_ih0 = (const float*)d_in[3];
  const float* w_hh0 = (const float*)d_in[4];
  const float* b_ih0 = (const float*)d_in[5];
  const float* b_hh0 = (const float*)d_in[6];
  const float* w_ih1 = (const float*)d_in[7];
  const float* w_hh1 = (const float*)d_in[8];
  const float* b_ih1 = (const float*)d_in[9];
  const float* b_hh1 = (const float*)d_in[10];
  const float* fc_w  = (const float*)d_in[11];
  const float* fc_b  = (const float*)d_in[12];
  float* out = (float*)d_out;
  float* ws  = (float*)d_ws;

  // ws layout (floats)
  float* xp   = ws;                       // [S][B][4H] = 8,388,608 (xp0, reused as xp1)
  float* h1s  = ws + 8388608;             // [S][B][H]  = 2,097,152
  float* h2s  = ws + 10485760;            // 2,097,152
  float* hbA  = ws + 12582912;            // [B][H] ping
  float* hbB  = ws + 12591104;            // [B][H] pong
  float* cbuf = ws + 12599296;            // [B][H]
  __bf16* Ahi = (__bf16*)(ws + 12607488); // [2048][1024] bf16
  __bf16* Alo = (__bf16*)(ws + 13656064); // [2048][1024] bf16
  // total ws: ~58.9 MB

  const size_t LOG = (size_t)2048 * VN;   // 65,536,000
  float* hn = out + LOG;                  // [2][8][1024]
  float* cn = out + LOG + 16384;          // [2][8][1024]

  k_gather<<<SN * BN, 256, 0, stream>>>(x, w_ih0, b_ih0, b_hh0, xp);

  // ---- layer 0 ----
  for (int t = 0; t < SN; ++t) {
    const float* hin = (t == 0) ? h0 : ((t & 1) ? hbB : hbA);
    float* hout = (t & 1) ? hbA : hbB;
    const float* cin = (t == 0) ? c0 : cbuf;
    k_step<<<256, 256, 0, stream>>>(xp + (size_t)t * BN * H4N, w_hh0, hin, hout,
                                    cin, cbuf, h1s + (size_t)t * BN * HN,
                                    hn, cn, t == SN - 1);
  }

  k_split<<<2048, 256, 0, stream>>>(h1s, Ahi, Alo);
  // xp1 = h1s @ w_ih1^T + (b_ih1 + b_hh1)   (M=2048, N=4096)
  k_gemm<<<16 * 32, 256, 0, stream>>>(Ahi, Alo, w_ih1, b_ih1, b_hh1, xp,
                                      16, H4N, 0);

  // ---- layer 1 ----
  for (int t = 0; t < SN; ++t) {
    const float* hin = (t == 0) ? (h0 + BN * HN) : ((t & 1) ? hbB : hbA);
    float* hout = (t & 1) ? hbA : hbB;
    const float* cin = (t == 0) ? (c0 + BN * HN) : cbuf;
    k_step<<<256, 256, 0, stream>>>(xp + (size_t)t * BN * H4N, w_hh1, hin, hout,
                                    cin, cbuf, h2s + (size_t)t * BN * HN,
                                    hn + BN * HN, cn + BN * HN, t == SN - 1);
  }

  k_split<<<2048, 256, 0, stream>>>(h2s, Ahi, Alo);
  // logits = h2s @ fc_w^T + fc_b  (M=2048, N=32000), row-permuted to b*S+t
  k_gemm<<<16 * 250, 256, 0, stream>>>(Ahi, Alo, fc_w, fc_b, nullptr, out,
                                       16, VN, 1);
}